// Round 3
// baseline (5640.439 us; speedup 1.0000x reference)
//
#include <hip/hip_runtime.h>

#define BB 128   // batch
#define SS 128   // seq
#define EE 256   // enc dim
#define DD 256   // lstm hidden
#define OO 64    // out dim

// bf16 weight buffer layout (ushort offsets) inside d_out scratch
#define W1_OFF   0         // 768*256   = 196608 (rows: Wh|Wc|We)
#define WHH_OFF  196608    // 256*1024  = 262144
#define WIH_OFF  458752    // 64*1024   = 65536
#define FCW_OFF  524288    // 320*64    = 20480
#define WTOTAL   544768

__device__ __forceinline__ float fsig(float x) { return 1.0f / (1.0f + __expf(-x)); }
__device__ __forceinline__ float ftanh(float x) {
    float t = __expf(-2.0f * fabsf(x));
    float r = (1.0f - t) / (1.0f + t);
    return copysignf(r, x);
}
__device__ __forceinline__ float bflo(unsigned int u) { return __uint_as_float(u << 16); }
__device__ __forceinline__ float bfhi(unsigned int u) { return __uint_as_float(u & 0xffff0000u); }

__device__ __forceinline__ void fma8(const uint4 w, const float xv, float* acc) {
    acc[0] += xv * bflo(w.x); acc[1] += xv * bfhi(w.x);
    acc[2] += xv * bflo(w.y); acc[3] += xv * bfhi(w.y);
    acc[4] += xv * bflo(w.z); acc[5] += xv * bfhi(w.z);
    acc[6] += xv * bflo(w.w); acc[7] += xv * bfhi(w.w);
}

// fp32 -> bf16 (RNE) weight conversion, runs every launch (graph-safe, same work)
__global__ __launch_bounds__(256) void conv_kernel(
    const float* __restrict__ W1, const float* __restrict__ Whh,
    const float* __restrict__ Wih, const float* __restrict__ fcW,
    unsigned short* __restrict__ out)
{
    const int idx = blockIdx.x * 256 + threadIdx.x;
    float f;
    if      (idx < WHH_OFF)  f = W1[idx];
    else if (idx < WIH_OFF)  f = Whh[idx - WHH_OFF];
    else if (idx < FCW_OFF)  f = Wih[idx - WIH_OFF];
    else if (idx < WTOTAL)   f = fcW[idx - FCW_OFF];
    else return;
    unsigned int u = __float_as_uint(f);
    u = (u + 0x7fffu + ((u >> 16) & 1u)) >> 16;
    out[idx] = (unsigned short)u;
}

// One block (512 thr, 8 waves) per batch row; whole scan block-local.
// enc_proj (fp32) lives in LDS; launch_bounds(512,2) -> 256-VGPR budget for deep MLP.
__global__ __launch_bounds__(512, 2) void scan_kernel(
    const float* __restrict__ inp,   // B,S,E
    const float* __restrict__ yhist, // B,S,OO
    const float* __restrict__ h0, const float* __restrict__ c0,
    const float* __restrict__ W1f,   // fp32 W1 (only We rows used here, init)
    const float* __restrict__ b1, const float* __restrict__ w2, const float* __restrict__ b2,
    const float* __restrict__ bih, const float* __restrict__ bhh,
    const float* __restrict__ fcb,
    const unsigned short* __restrict__ wbf,  // bf16 weights (see *_OFF)
    float* __restrict__ hctxT)       // ws: [512][128] (0..255 h, 256..511 ctx)
{
    __shared__ float sh_enc[SS * 260];     // 133120 B  enc_proj+b1, row stride 260
    __shared__ float red1a[4096];          // 16384 B   [16][256] P1 partials / [4][1024] gates
    __shared__ float red1b[1024];          // 4096 B    [4][256] ctx partials / [16][64] yt partials
    __shared__ float sh_h[DD], sh_c[DD];   // 2048
    __shared__ float sh_hc[EE], sh_w2[EE]; // 2048 (plain layout)
    __shared__ float sh_raw[132];          // exp(scores) [0..127], denom recip at [128]
    __shared__ float sh_ctx[EE];           // 1024
    __shared__ float sh_y[OO], sh_yt[OO];  // 512
    // total ~159.8 KB -> exactly 1 block/CU

    const int b = blockIdx.x, t = threadIdx.x;
    const float* inp_b = inp + (size_t)b * SS * EE;
    const unsigned short* W1bf  = wbf + W1_OFF;
    const unsigned short* Whhbf = wbf + WHH_OFF;
    const unsigned short* Wihbf = wbf + WIH_OFF;
    const unsigned short* fcWbf = wbf + FCW_OFF;
    const float b2v = b2[0];

    // role constants (512 threads)
    const int kc1 = t >> 5, e8 = (t & 31) * 8;        // P1: 16 kg x 32 k, 8 cols (uint4)
    const int kc2 = t >> 7, j8 = (t & 127) * 8;       // P1b/P4: 4 kg, 8 cols (uint4) - coalesced
    const int s_own = t >> 2, a2 = t & 3;             // P2: 4 thr/s, 64 dims each
    const int sg3 = t >> 7, c2 = (t & 127) * 2;       // P3: 4 sg x 32 s, 2 cols
    const int kg = t >> 5, c2b = (t & 31) * 2;        // P3b: 16 kg x 20 k, 2 cols

    if (t < 256) {
        sh_h[t] = h0[b * 256 + t]; sh_c[t] = c0[b * 256 + t];
        sh_w2[t] = w2[t];
        sh_hc[t] = b1[t];               // staged for enc_proj fold
    }
    float bs_r[8];
    #pragma unroll
    for (int r = 0; r < 8; ++r) bs_r[r] = 0.f;
    if (t < 128) {                       // kc2==0 threads seed the LSTM biases
        #pragma unroll
        for (int r = 0; r < 8; ++r) bs_r[r] = bih[t * 8 + r] + bhh[t * 8 + r];
    }
    const float fcb_reg = (t < 64) ? fcb[t] : 0.f;
    __syncthreads();

    // ---- enc_proj (+b1) into LDS (fp32). Per thread: (s_own, dims a2*64..+64). ----
    {
        float4 ec[16];
        #pragma unroll
        for (int d = 0; d < 16; ++d) ec[d] = make_float4(0.f, 0.f, 0.f, 0.f);
        const float* We = W1f + 512 * 256;
        for (int kc = 0; kc < 16; ++kc) {
            {   // stage We rows [kc*16,+16) x 256 -> red1a
                const int row = t >> 5, c8 = (t & 31) * 8;
                *(float4*)&red1a[row * 256 + c8] =
                    *(const float4*)(We + (size_t)(kc * 16 + row) * 256 + c8);
                *(float4*)&red1a[row * 256 + c8 + 4] =
                    *(const float4*)(We + (size_t)(kc * 16 + row) * 256 + c8 + 4);
            }
            float4 xq = *(const float4*)(inp_b + (size_t)s_own * 256 + kc * 16 + a2 * 4);
            __syncthreads();
            #pragma unroll
            for (int q = 0; q < 4; ++q) {
                const int src = (t & 60) | q;   // quad lane q within this wave
                float4 xs;
                xs.x = __shfl(xq.x, src, 64); xs.y = __shfl(xq.y, src, 64);
                xs.z = __shfl(xq.z, src, 64); xs.w = __shfl(xq.w, src, 64);
                const float xv[4] = {xs.x, xs.y, xs.z, xs.w};
                #pragma unroll
                for (int j = 0; j < 4; ++j) {
                    const int krow = q * 4 + j;
                    #pragma unroll
                    for (int d = 0; d < 16; ++d) {
                        float4 w = *(const float4*)&red1a[krow * 256 + a2 * 64 + d * 4];
                        ec[d].x += xv[j] * w.x; ec[d].y += xv[j] * w.y;
                        ec[d].z += xv[j] * w.z; ec[d].w += xv[j] * w.w;
                    }
                }
            }
            __syncthreads();
        }
        #pragma unroll
        for (int d = 0; d < 16; ++d) {
            float4 bv = *(const float4*)&sh_hc[a2 * 64 + d * 4];
            float4 v;
            v.x = ec[d].x + bv.x; v.y = ec[d].y + bv.y;
            v.z = ec[d].z + bv.z; v.w = ec[d].w + bv.w;
            *(float4*)&sh_enc[s_own * 260 + a2 * 64 + d * 4] = v;
        }
        __syncthreads();
    }

    for (int ts = 0; ts < SS; ++ts) {
        // ---- P1: hc partials [16][256] -> red1a (coalesced: wave = 2 rows x 512B)
        {
            float acc[8];
            #pragma unroll
            for (int r = 0; r < 8; ++r) acc[r] = 0.f;
            #pragma unroll 8
            for (int k = kc1 * 32; k < kc1 * 32 + 32; ++k) {
                const float xv = (k < 256) ? sh_h[k] : sh_c[k - 256];
                uint4 w = *(const uint4*)(W1bf + (size_t)k * 256 + e8);
                fma8(w, xv, acc);
            }
            *(float4*)&red1a[kc1 * 256 + e8]     = make_float4(acc[0], acc[1], acc[2], acc[3]);
            *(float4*)&red1a[kc1 * 256 + e8 + 4] = make_float4(acc[4], acc[5], acc[6], acc[7]);
        }
        if (t >= 448) sh_y[t - 448] = yhist[(size_t)b * SS * OO + ts * OO + (t - 448)];
        __syncthreads();                                 // bar A
        if (t < 256) {
            float v = 0.f;
            #pragma unroll
            for (int r = 0; r < 16; ++r) v += red1a[r * 256 + t];
            sh_hc[t] = v;                                // b1 already in sh_enc
        }
        __syncthreads();                                 // bar B

        // ---- P1b (Whh, coalesced uint4; partials stay in regs until P4) + P2 fused
        float g[8];
        #pragma unroll
        for (int r = 0; r < 8; ++r) g[r] = bs_r[r];
        #pragma unroll 8
        for (int k = kc2 * 64; k < kc2 * 64 + 64; ++k) {
            const float hv = sh_h[k];
            uint4 w = *(const uint4*)(Whhbf + (size_t)k * 1024 + j8);
            fma8(w, hv, g);
        }
        {   // P2: scores; rotated reads (2-way max on hc/w2, 4-way on enc)
            float sacc = 0.f;
            #pragma unroll
            for (int d = 0; d < 16; ++d) {
                const int base = a2 * 64 + ((d * 4 + 16 * a2) & 63);
                float4 e4v = *(const float4*)&sh_enc[s_own * 260 + base];
                float4 hc4 = *(const float4*)&sh_hc[base];
                float4 w24 = *(const float4*)&sh_w2[base];
                sacc += ftanh(e4v.x + hc4.x) * w24.x;
                sacc += ftanh(e4v.y + hc4.y) * w24.y;
                sacc += ftanh(e4v.z + hc4.z) * w24.z;
                sacc += ftanh(e4v.w + hc4.w) * w24.w;
            }
            sacc += __shfl_xor(sacc, 1);
            sacc += __shfl_xor(sacc, 2);
            if (a2 == 0) sh_raw[s_own] = __expf(sacc + b2v);  // max-free: |score| <= sum|w2| ~ 10
        }
        __syncthreads();                                 // bar C

        // ---- P3: context partials [4][256] (inp from global, L2-hot) + denom
        {
            float ax = 0.f, ay = 0.f;
            #pragma unroll 4
            for (int i = 0; i < 32; ++i) {
                const int s = sg3 * 32 + i;
                const float al = sh_raw[s];
                float2 iv = *(const float2*)(inp_b + (size_t)s * 256 + c2);
                ax += al * iv.x; ay += al * iv.y;
            }
            *(float2*)&red1b[sg3 * 256 + c2] = make_float2(ax, ay);
        }
        if (t < 64) {
            float v = sh_raw[t] + sh_raw[t + 64];
            #pragma unroll
            for (int m = 32; m > 0; m >>= 1) v += __shfl_xor(v, m);
            if (t == 0) sh_raw[128] = 1.0f / v;
        }
        __syncthreads();                                 // bar D
        if (t < 256) {
            float v = 0.f;
            #pragma unroll
            for (int r = 0; r < 4; ++r) v += red1b[r * 256 + t];
            v *= sh_raw[128];
            sh_ctx[t] = v;
            if (ts == SS - 1) hctxT[(size_t)(256 + t) * 128 + b] = v;
        }
        __syncthreads();                                 // bar E

        // ---- P3b: y_tilde partials [16][64] -> red1b
        {
            float a0 = 0.f, a1 = 0.f;
            #pragma unroll
            for (int kk = kg * 20; kk < kg * 20 + 20; ++kk) {
                const float val = (kk < 256) ? sh_ctx[kk] : sh_y[kk - 256];
                unsigned int w = *(const unsigned int*)(fcWbf + kk * 64 + c2b);
                a0 += val * bflo(w); a1 += val * bfhi(w);
            }
            *(float2*)&red1b[kg * 64 + c2b] = make_float2(a0, a1);
        }
        __syncthreads();                                 // bar F
        if (t < 64) {
            float v = fcb_reg;
            #pragma unroll
            for (int r = 0; r < 16; ++r) v += red1b[r * 64 + t];
            sh_yt[t] = v;
        }
        __syncthreads();                                 // bar G

        // ---- P4: Wih gate terms into g (coalesced uint4); single store
        #pragma unroll
        for (int i = 0; i < 16; ++i) {
            const float yv = sh_yt[kc2 * 16 + i];
            uint4 w = *(const uint4*)(Wihbf + (size_t)(kc2 * 16 + i) * 1024 + j8);
            fma8(w, yv, g);
        }
        *(float4*)&red1a[kc2 * 1024 + j8]     = make_float4(g[0], g[1], g[2], g[3]);
        *(float4*)&red1a[kc2 * 1024 + j8 + 4] = make_float4(g[4], g[5], g[6], g[7]);
        __syncthreads();                                 // bar H

        // ---- gates reduce + elementwise (merged)
        if (t < 256) {
            float gq[4];
            #pragma unroll
            for (int q = 0; q < 4; ++q) {
                float v = 0.f;
                #pragma unroll
                for (int r = 0; r < 4; ++r) v += red1a[r * 1024 + q * 256 + t];
                gq[q] = v;
            }
            const float cn = fsig(gq[1]) * sh_c[t] + fsig(gq[0]) * ftanh(gq[2]);
            sh_c[t] = cn;
            const float hn = fsig(gq[3]) * ftanh(cn);
            sh_h[t] = hn;
            if (ts == SS - 1) hctxT[(size_t)t * 128 + b] = hn;
        }
        __syncthreads();                                 // bar I
    }
}

// out(128 x 8192) = A(128x512, stored transposed AT[512][128]) @ W(512x8192) + bias
__global__ __launch_bounds__(256) void out_gemm(
    const float* __restrict__ AT, const float* __restrict__ W,
    const float* __restrict__ bias, float* __restrict__ out)
{
    __shared__ float Ab[64 * 132];  // [k][m]
    __shared__ float Bb[64 * 32];   // [k][n]
    const int t = threadIdx.x;
    const int nt = blockIdx.x * 32;
    const int n4 = (t & 7) * 4;
    const int m4 = (t >> 3) * 4;
    float acc[4][4];
    #pragma unroll
    for (int i = 0; i < 4; ++i)
        #pragma unroll
        for (int jj = 0; jj < 4; ++jj) acc[i][jj] = 0.f;

    for (int kc = 0; kc < 8; ++kc) {
        #pragma unroll
        for (int i = 0; i < 8; ++i) {
            const int flat4 = i * 256 + t;
            const int row = flat4 >> 5, mm4 = (flat4 & 31) * 4;
            float4 v = *(const float4*)(AT + (size_t)(kc * 64 + row) * 128 + mm4);
            *(float4*)&Ab[row * 132 + mm4] = v;
        }
        #pragma unroll
        for (int i = 0; i < 2; ++i) {
            const int fl = t + i * 256;
            const int k = fl >> 3, nn4 = (fl & 7) * 4;
            *(float4*)&Bb[k * 32 + nn4] =
                *(const float4*)(W + (size_t)(kc * 64 + k) * 8192 + nt + nn4);
        }
        __syncthreads();
        for (int k = 0; k < 64; ++k) {
            const float4 bv = *(const float4*)&Bb[k * 32 + n4];
            const float4 av = *(const float4*)&Ab[k * 132 + m4];
            acc[0][0] += av.x * bv.x; acc[0][1] += av.x * bv.y; acc[0][2] += av.x * bv.z; acc[0][3] += av.x * bv.w;
            acc[1][0] += av.y * bv.x; acc[1][1] += av.y * bv.y; acc[1][2] += av.y * bv.z; acc[1][3] += av.y * bv.w;
            acc[2][0] += av.z * bv.x; acc[2][1] += av.z * bv.y; acc[2][2] += av.z * bv.z; acc[2][3] += av.z * bv.w;
            acc[3][0] += av.w * bv.x; acc[3][1] += av.w * bv.y; acc[3][2] += av.w * bv.z; acc[3][3] += av.w * bv.w;
        }
        __syncthreads();
    }
    const float4 bb = *(const float4*)(bias + nt + n4);
    #pragma unroll
    for (int i = 0; i < 4; ++i) {
        float4 r;
        r.x = acc[i][0] + bb.x; r.y = acc[i][1] + bb.y;
        r.z = acc[i][2] + bb.z; r.w = acc[i][3] + bb.w;
        *(float4*)(out + (size_t)(m4 + i) * 8192 + nt + n4) = r;
    }
}

extern "C" void kernel_launch(void* const* d_in, const int* in_sizes, int n_in,
                              void* d_out, int out_size, void* d_ws, size_t ws_size,
                              hipStream_t stream) {
    const float* inp = (const float*)d_in[0];
    const float* yh  = (const float*)d_in[1];
    const float* h0  = (const float*)d_in[2];
    const float* c0  = (const float*)d_in[3];
    const float* W1  = (const float*)d_in[4];
    const float* b1  = (const float*)d_in[5];
    const float* w2  = (const float*)d_in[6];
    const float* b2  = (const float*)d_in[7];
    const float* Wih = (const float*)d_in[8];
    const float* Whh = (const float*)d_in[9];
    const float* bih = (const float*)d_in[10];
    const float* bhh = (const float*)d_in[11];
    const float* fcW = (const float*)d_in[12];
    const float* fcb = (const float*)d_in[13];
    const float* foW = (const float*)d_in[14];
    const float* fob = (const float*)d_in[15];

    float* hctxT = (float*)d_ws;                    // 256 KB (proven)
    unsigned short* wbf = (unsigned short*)d_out;   // 1.09 MB bf16 weights in d_out scratch
                                                    // (overwritten by out_gemm at the end)

    conv_kernel<<<dim3((WTOTAL + 255) / 256), dim3(256), 0, stream>>>(W1, Whh, Wih, fcW, wbf);
    scan_kernel<<<dim3(BB), dim3(512), 0, stream>>>(
        inp, yh, h0, c0, W1, b1, w2, b2, bih, bhh, fcb, wbf, hctxT);
    out_gemm<<<dim3(8192 / 32), dim3(256), 0, stream>>>(hctxT, foW, fob, (float*)d_out);
}

// Round 5
// 5418.689 us; speedup vs baseline: 1.0409x; 1.0409x over previous
//
#include <hip/hip_runtime.h>

#define BB 128   // batch
#define SS 128   // seq
#define EE 256   // enc dim
#define DD 256   // lstm hidden
#define OO 64    // out dim

// bf16 weight buffer layout (ushort offsets) inside d_out scratch
#define W1_OFF   0         // 768*256   = 196608 (rows: Wh|Wc|We)
#define WHH_OFF  196608    // 256*1024  = 262144
#define WIH_OFF  458752    // 64*1024   = 65536
#define FCW_OFF  524288    // 320*64    = 20480
#define WTOTAL   544768

// Pin a loaded value into a VGPR at this program point: forbids the compiler
// from sinking/rematerializing the load later (ERRATA#17-style liveness asm).
// NOTE: parameter must NOT be named x/y/z/w (token substitution inside member access).
#define PIN4(v_) asm volatile("" : "+v"((v_).x), "+v"((v_).y), "+v"((v_).z), "+v"((v_).w))
#define PIN1(v_) asm volatile("" : "+v"(v_))

__device__ __forceinline__ float fsig(float x) { return 1.0f / (1.0f + __expf(-x)); }
__device__ __forceinline__ float ftanh(float x) {
    float t = __expf(-2.0f * fabsf(x));
    float r = (1.0f - t) / (1.0f + t);
    return copysignf(r, x);
}
// swizzle within 32-float groups (rotation by 4*(group)): conflict-free strided access
__device__ __forceinline__ int SWZ(int e) { return (e & ~31) | ((e + 4 * (e >> 5)) & 31); }
__device__ __forceinline__ float bflo(unsigned int u) { return __uint_as_float(u << 16); }
__device__ __forceinline__ float bfhi(unsigned int u) { return __uint_as_float(u & 0xffff0000u); }

__device__ __forceinline__ void fma8(const uint4 w, const float xv, float* acc) {
    acc[0] += xv * bflo(w.x); acc[1] += xv * bfhi(w.x);
    acc[2] += xv * bflo(w.y); acc[3] += xv * bfhi(w.y);
    acc[4] += xv * bflo(w.z); acc[5] += xv * bfhi(w.z);
    acc[6] += xv * bflo(w.w); acc[7] += xv * bfhi(w.w);
}

// fp32 -> bf16 (RNE) weight conversion, runs every launch (graph-safe, same work)
__global__ __launch_bounds__(256) void conv_kernel(
    const float* __restrict__ W1, const float* __restrict__ Whh,
    const float* __restrict__ Wih, const float* __restrict__ fcW,
    unsigned short* __restrict__ out)
{
    const int idx = blockIdx.x * 256 + threadIdx.x;
    float f;
    if      (idx < WHH_OFF)  f = W1[idx];
    else if (idx < WIH_OFF)  f = Whh[idx - WHH_OFF];
    else if (idx < FCW_OFF)  f = Wih[idx - WIH_OFF];
    else if (idx < WTOTAL)   f = fcW[idx - FCW_OFF];
    else return;
    unsigned int u = __float_as_uint(f);
    u = (u + 0x7fffu + ((u >> 16) & 1u)) >> 16;
    out[idx] = (unsigned short)u;
}

// One block (1024 thr, 16 waves) per batch row; whole scan block-local.
// R0 structure + explicit pinned register-batched weight streams (MLP fix).
__global__ __launch_bounds__(1024, 4) void scan_kernel(
    const float* __restrict__ inp,   // B,S,E
    const float* __restrict__ yhist, // B,S,OO
    const float* __restrict__ h0, const float* __restrict__ c0,
    const float* __restrict__ W1f,   // fp32 W1 (only We rows used here, init)
    const float* __restrict__ b1, const float* __restrict__ w2, const float* __restrict__ b2,
    const float* __restrict__ bih, const float* __restrict__ bhh,
    const float* __restrict__ fcb,
    const unsigned short* __restrict__ wbf,  // bf16 weights (see *_OFF)
    float* __restrict__ hctxT)       // ws: [512][128] (0..255 h, 256..511 ctx)
{
    __shared__ float sh_h[DD], sh_c[DD], sh_hc[EE];      // sh_hc stored SWZ'd
    __shared__ float sh_gh[1024];
    __shared__ float sh_w2[EE];                          // SWZ'd
    __shared__ float sh_b1[EE], sh_bs[1024];
    __shared__ float sh_raw[SS];                         // exp(scores)
    __shared__ float sh_ctx[EE], sh_y[OO], sh_yt[OO], sh_fcb[OO];
    __shared__ float sh_misc[1];
    __shared__ float red1[32 * 256];                     // 8192
    __shared__ float red2[8 * 1024];                     // 8192

    const int b = blockIdx.x, t = threadIdx.x;
    const float* inp_b = inp + (size_t)b * SS * EE;
    const unsigned short* W1bf  = wbf + W1_OFF;
    const unsigned short* Whhbf = wbf + WHH_OFF;
    const unsigned short* Wihbf = wbf + WIH_OFF;
    const unsigned short* fcWbf = wbf + FCW_OFF;
    const float b2v = b2[0];

    // role constants
    const int e8  = (t & 31) * 8,  kc1 = t >> 5;   // P1
    const int j8  = (t & 127) * 8, kc2 = t >> 7;   // P1b / P4
    const int s_own = t >> 3,      a2  = t & 7, e0 = a2 * 32;  // P2
    const int e4  = (t & 63) * 4,  sc  = t >> 6;   // P3
    const int o4  = (t & 15) * 4,  kc3 = t >> 4;   // P3b

    if (t < 256) {
        sh_h[t] = h0[b * 256 + t]; sh_c[t] = c0[b * 256 + t];
        sh_b1[t] = b1[t];
        sh_w2[SWZ(t)] = w2[t];
    }
    if (t < 64) sh_fcb[t] = fcb[t];
    sh_bs[t] = bih[t] + bhh[t];

    // ---- enc_proj into registers via LDS-staged chunks (fp32 We, one-time) ----
    float er[32];
    #pragma unroll
    for (int j = 0; j < 32; ++j) er[j] = 0.f;
    {
        const float* We = W1f + 512 * 256;
        for (int kc = 0; kc < 16; ++kc) {
            {   // stage We rows [kc*16,+16) x 256 -> red1[0..4095]
                const int row = t >> 6, c4 = (t & 63) * 4;
                float4 v = *(const float4*)(We + (size_t)(kc * 16 + row) * 256 + c4);
                *(float4*)&red1[row * 256 + c4] = v;
            }
            {   // stage inp cols [kc*16,+16) for all 128 s -> red1[4096..6143]
                const int s = t >> 3, k2 = (t & 7) * 2;
                float2 v = *(const float2*)(inp_b + s * 256 + kc * 16 + k2);
                red1[4096 + s * 16 + k2] = v.x;
                red1[4096 + s * 16 + k2 + 1] = v.y;
            }
            __syncthreads();
            for (int k = 0; k < 16; ++k) {
                const float xv = red1[4096 + s_own * 16 + k];
                #pragma unroll
                for (int j4 = 0; j4 < 8; ++j4) {
                    float4 w = *(const float4*)&red1[k * 256 + e0 + j4 * 4];
                    er[j4*4+0] += xv * w.x; er[j4*4+1] += xv * w.y;
                    er[j4*4+2] += xv * w.z; er[j4*4+3] += xv * w.w;
                }
            }
            __syncthreads();
        }
    }

    // ---- step-invariant stream bases ----
    const unsigned short* W1p1  = W1bf  + (size_t)(kc1 * 16) * 256 + e8;    // P1 rows
    const unsigned short* Whhp  = Whhbf + (size_t)(kc2 * 32) * 1024 + j8;   // P1b rows
    const unsigned short* Wihp  = Wihbf + (size_t)(kc2 * 8) * 1024 + j8;    // P4 rows

    // prologue: prefetch P1 batch0 + first yhist row
    uint4 p1w[8];
    #pragma unroll
    for (int i = 0; i < 8; ++i) { p1w[i] = *(const uint4*)(W1p1 + i * 256); PIN4(p1w[i]); }
    float yreg = 0.f;
    if (t < 64) yreg = yhist[(size_t)b * SS * OO + t];

    for (int ts = 0; ts < SS; ++ts) {
        if (t < 64) sh_y[t] = yreg;   // prefetched last step (no exposed miss at bar A)

        // ---- P1: hc partials [32][256] -> red1 (2 pinned batches of 8 uint4)
        {
            float acc[8];
            #pragma unroll
            for (int r = 0; r < 8; ++r) acc[r] = 0.f;
            uint4 wb1[8];
            #pragma unroll
            for (int i = 0; i < 8; ++i) wb1[i] = *(const uint4*)(W1p1 + (8 + i) * 256);
            const float* xsrc = (kc1 < 16) ? &sh_h[kc1 * 16] : &sh_c[kc1 * 16 - 256];
            float xv[16];
            #pragma unroll
            for (int i = 0; i < 16; ++i) xv[i] = xsrc[i];
            #pragma unroll
            for (int i = 0; i < 8; ++i) fma8(p1w[i], xv[i], acc);
            #pragma unroll
            for (int i = 0; i < 8; ++i) PIN4(wb1[i]);
            #pragma unroll
            for (int i = 0; i < 8; ++i) fma8(wb1[i], xv[8 + i], acc);
            *(float4*)&red1[kc1 * 256 + e8]     = make_float4(acc[0], acc[1], acc[2], acc[3]);
            *(float4*)&red1[kc1 * 256 + e8 + 4] = make_float4(acc[4], acc[5], acc[6], acc[7]);
        }
        // ---- P1b: gh partials [8][1024] -> red2 (4 pinned batches of 8 uint4)
        {
            float acc[8];
            #pragma unroll
            for (int r = 0; r < 8; ++r) acc[r] = 0.f;
            const float* hsrc = &sh_h[kc2 * 32];
            #pragma unroll
            for (int c = 0; c < 4; ++c) {
                uint4 wb[8];
                #pragma unroll
                for (int i = 0; i < 8; ++i) wb[i] = *(const uint4*)(Whhp + (c * 8 + i) * 1024);
                float hv[8];
                #pragma unroll
                for (int i = 0; i < 8; ++i) hv[i] = hsrc[c * 8 + i];
                #pragma unroll
                for (int i = 0; i < 8; ++i) PIN4(wb[i]);
                #pragma unroll
                for (int i = 0; i < 8; ++i) fma8(wb[i], hv[i], acc);
            }
            *(float4*)&red2[kc2 * 1024 + j8]     = make_float4(acc[0], acc[1], acc[2], acc[3]);
            *(float4*)&red2[kc2 * 1024 + j8 + 4] = make_float4(acc[4], acc[5], acc[6], acc[7]);
        }
        __syncthreads();
        if (t < 256) {
            float v = sh_b1[t];
            #pragma unroll 8
            for (int kc = 0; kc < 32; ++kc) v += red1[kc * 256 + t];
            sh_hc[SWZ(t)] = v;
        }
        {
            float v = 0.f;
            #pragma unroll
            for (int kc = 0; kc < 8; ++kc) v += red2[kc * 1024 + t];
            sh_gh[t] = v;
        }
        __syncthreads();

        // ---- issue P4's Wih batch now (addresses step-invariant; used 5 bars later)
        uint4 wih[8];
        #pragma unroll
        for (int i = 0; i < 8; ++i) wih[i] = *(const uint4*)(Wihp + i * 1024);

        // ---- P2: scores from register er + swizzled hc/w2 (conflict-free)
        {
            float acc = 0.f;
            #pragma unroll
            for (int j4 = 0; j4 < 8; ++j4) {
                const int phys = e0 + ((j4 * 4 + 4 * a2) & 31);
                float4 hc4 = *(const float4*)&sh_hc[phys];
                float4 w24 = *(const float4*)&sh_w2[phys];
                acc += ftanh(er[j4*4+0] + hc4.x) * w24.x;
                acc += ftanh(er[j4*4+1] + hc4.y) * w24.y;
                acc += ftanh(er[j4*4+2] + hc4.z) * w24.z;
                acc += ftanh(er[j4*4+3] + hc4.w) * w24.w;
            }
            acc += __shfl_xor(acc, 1);
            acc += __shfl_xor(acc, 2);
            acc += __shfl_xor(acc, 4);
            if (a2 == 0) sh_raw[s_own] = __expf(acc + b2v);  // max-free: |score| <= sum|w2| ~ 10
        }
        #pragma unroll
        for (int i = 0; i < 8; ++i) PIN4(wih[i]);   // materialize Wih here, hold to P4
        __syncthreads();
        if (t < 64) {
            float v = sh_raw[t] + sh_raw[t + 64];
            #pragma unroll
            for (int m = 32; m > 0; m >>= 1) v += __shfl_xor(v, m);
            if (t == 0) sh_misc[0] = 1.0f / v;
        }
        __syncthreads();

        // ---- P3: context partials [16][256] -> red1 (batched inp loads) + y prefetch
        {
            float4 iv[8];
            #pragma unroll
            for (int i = 0; i < 8; ++i)
                iv[i] = *(const float4*)(inp_b + (size_t)(sc * 8 + i) * 256 + e4);
            if (t < 64) {
                const int tn = (ts + 1) & (SS - 1);
                yreg = yhist[(size_t)b * SS * OO + tn * OO + t];
                PIN1(yreg);
            }
            float al[8];
            #pragma unroll
            for (int i = 0; i < 8; ++i) al[i] = sh_raw[sc * 8 + i];
            #pragma unroll
            for (int i = 0; i < 8; ++i) PIN4(iv[i]);
            float ax = 0.f, ay = 0.f, az = 0.f, aw = 0.f;
            #pragma unroll
            for (int i = 0; i < 8; ++i) {
                ax += al[i] * iv[i].x; ay += al[i] * iv[i].y;
                az += al[i] * iv[i].z; aw += al[i] * iv[i].w;
            }
            *(float4*)&red1[sc * 256 + e4] = make_float4(ax, ay, az, aw);
        }
        __syncthreads();
        if (t < 256) {
            float v = 0.f;
            #pragma unroll
            for (int k = 0; k < 16; ++k) v += red1[k * 256 + t];
            v *= sh_misc[0];
            sh_ctx[t] = v;
            if (ts == SS - 1) hctxT[(size_t)(256 + t) * 128 + b] = v;
        }
        __syncthreads();

        // ---- P3b: y_tilde partials [64][64] -> red1
        {
            float acc[4] = {0.f, 0.f, 0.f, 0.f};
            for (int kk = kc3 * 5; kk < kc3 * 5 + 5; ++kk) {
                const float val = (kk < 256) ? sh_ctx[kk] : sh_y[kk - 256];
                uint2 w = *(const uint2*)(fcWbf + kk * 64 + o4);
                acc[0] += val * bflo(w.x);
                acc[1] += val * bfhi(w.x);
                acc[2] += val * bflo(w.y);
                acc[3] += val * bfhi(w.y);
            }
            *(float4*)&red1[kc3 * 64 + o4] = make_float4(acc[0], acc[1], acc[2], acc[3]);
        }
        __syncthreads();
        if (t < 64) {
            float v = sh_fcb[t];
            #pragma unroll 16
            for (int kc = 0; kc < 64; ++kc) v += red1[kc * 64 + t];
            sh_yt[t] = v;
        }
        __syncthreads();

        // ---- P4: gate partials (Wih from pinned regs) [8][1024] -> red2
        {
            float yv[8];
            #pragma unroll
            for (int i = 0; i < 8; ++i) yv[i] = sh_yt[kc2 * 8 + i];
            float acc[8];
            #pragma unroll
            for (int r = 0; r < 8; ++r) acc[r] = 0.f;
            #pragma unroll
            for (int i = 0; i < 8; ++i) fma8(wih[i], yv[i], acc);
            *(float4*)&red2[kc2 * 1024 + j8]     = make_float4(acc[0], acc[1], acc[2], acc[3]);
            *(float4*)&red2[kc2 * 1024 + j8 + 4] = make_float4(acc[4], acc[5], acc[6], acc[7]);
        }
        // prefetch next step's P1 batch0 (addresses step-invariant)
        #pragma unroll
        for (int i = 0; i < 8; ++i) { p1w[i] = *(const uint4*)(W1p1 + i * 256); PIN4(p1w[i]); }
        __syncthreads();
        {
            float v = sh_gh[t] + sh_bs[t];
            #pragma unroll
            for (int kc = 0; kc < 8; ++kc) v += red2[kc * 1024 + t];
            red1[t] = v;   // gates[1024]
        }
        __syncthreads();
        if (t < 256) {
            const float gi = red1[t], gf = red1[256 + t], gg = red1[512 + t], go = red1[768 + t];
            const float cn = fsig(gf) * sh_c[t] + fsig(gi) * ftanh(gg);
            sh_c[t] = cn;
            const float hn = fsig(go) * ftanh(cn);
            sh_h[t] = hn;
            if (ts == SS - 1) hctxT[(size_t)t * 128 + b] = hn;
        }
        __syncthreads();
    }
}

// out(128 x 8192) = A(128x512, stored transposed AT[512][128]) @ W(512x8192) + bias
__global__ __launch_bounds__(256) void out_gemm(
    const float* __restrict__ AT, const float* __restrict__ W,
    const float* __restrict__ bias, float* __restrict__ out)
{
    __shared__ float Ab[64 * 132];  // [k][m]
    __shared__ float Bb[64 * 32];   // [k][n]
    const int t = threadIdx.x;
    const int nt = blockIdx.x * 32;
    const int n4 = (t & 7) * 4;
    const int m4 = (t >> 3) * 4;
    float acc[4][4];
    #pragma unroll
    for (int i = 0; i < 4; ++i)
        #pragma unroll
        for (int jj = 0; jj < 4; ++jj) acc[i][jj] = 0.f;

    for (int kc = 0; kc < 8; ++kc) {
        #pragma unroll
        for (int i = 0; i < 8; ++i) {
            const int flat4 = i * 256 + t;
            const int row = flat4 >> 5, mm4 = (flat4 & 31) * 4;
            float4 v = *(const float4*)(AT + (size_t)(kc * 64 + row) * 128 + mm4);
            *(float4*)&Ab[row * 132 + mm4] = v;
        }
        #pragma unroll
        for (int i = 0; i < 2; ++i) {
            const int fl = t + i * 256;
            const int k = fl >> 3, nn4 = (fl & 7) * 4;
            *(float4*)&Bb[k * 32 + nn4] =
                *(const float4*)(W + (size_t)(kc * 64 + k) * 8192 + nt + nn4);
        }
        __syncthreads();
        for (int k = 0; k < 64; ++k) {
            const float4 bv = *(const float4*)&Bb[k * 32 + n4];
            const float4 av = *(const float4*)&Ab[k * 132 + m4];
            acc[0][0] += av.x * bv.x; acc[0][1] += av.x * bv.y; acc[0][2] += av.x * bv.z; acc[0][3] += av.x * bv.w;
            acc[1][0] += av.y * bv.x; acc[1][1] += av.y * bv.y; acc[1][2] += av.y * bv.z; acc[1][3] += av.y * bv.w;
            acc[2][0] += av.z * bv.x; acc[2][1] += av.z * bv.y; acc[2][2] += av.z * bv.z; acc[2][3] += av.z * bv.w;
            acc[3][0] += av.w * bv.x; acc[3][1] += av.w * bv.y; acc[3][2] += av.w * bv.z; acc[3][3] += av.w * bv.w;
        }
        __syncthreads();
    }
    const float4 bb = *(const float4*)(bias + nt + n4);
    #pragma unroll
    for (int i = 0; i < 4; ++i) {
        float4 r;
        r.x = acc[i][0] + bb.x; r.y = acc[i][1] + bb.y;
        r.z = acc[i][2] + bb.z; r.w = acc[i][3] + bb.w;
        *(float4*)(out + (size_t)(m4 + i) * 8192 + nt + n4) = r;
    }
}

extern "C" void kernel_launch(void* const* d_in, const int* in_sizes, int n_in,
                              void* d_out, int out_size, void* d_ws, size_t ws_size,
                              hipStream_t stream) {
    const float* inp = (const float*)d_in[0];
    const float* yh  = (const float*)d_in[1];
    const float* h0  = (const float*)d_in[2];
    const float* c0  = (const float*)d_in[3];
    const float* W1  = (const float*)d_in[4];
    const float* b1  = (const float*)d_in[5];
    const float* w2  = (const float*)d_in[6];
    const float* b2  = (const float*)d_in[7];
    const float* Wih = (const float*)d_in[8];
    const float* Whh = (const float*)d_in[9];
    const float* bih = (const float*)d_in[10];
    const float* bhh = (const float*)d_in[11];
    const float* fcW = (const float*)d_in[12];
    const float* fcb = (const float*)d_in[13];
    const float* foW = (const float*)d_in[14];
    const float* fob = (const float*)d_in[15];

    float* hctxT = (float*)d_ws;                    // 256 KB (proven)
    unsigned short* wbf = (unsigned short*)d_out;   // 1.09 MB bf16 weights in d_out scratch
                                                    // (overwritten by out_gemm at the end)

    conv_kernel<<<dim3((WTOTAL + 255) / 256), dim3(256), 0, stream>>>(W1, Whh, Wih, fcW, wbf);
    scan_kernel<<<dim3(BB), dim3(1024), 0, stream>>>(
        inp, yh, h0, c0, W1, b1, w2, b2, bih, bhh, fcb, wbf, hctxT);
    out_gemm<<<dim3(8192 / 32), dim3(256), 0, stream>>>(hctxT, foW, fob, (float*)d_out);
}